// Round 3
// baseline (2237.884 us; speedup 1.0000x reference)
//
#include <hip/hip_runtime.h>
#include <math.h>

#define MSZ 1048576ull   // 1024*1024 elements per matrix slot
#define NMAT 33          // matrix 0 = L0, matrices 1..32 = per-batch L

__device__ __forceinline__ float frcp(float x){ return __builtin_amdgcn_rcpf(x); }

typedef __attribute__((ext_vector_type(8)))  short bfrag;    // 8 x bf16 (4 VGPR)
typedef __attribute__((ext_vector_type(16))) float f32x16;   // 32x32 acc

__device__ __forceinline__ unsigned short bf16rn(float x){
  unsigned u = __float_as_uint(x);
  unsigned r = u + 0x7fffu + ((u>>16)&1u);
  return (unsigned short)(r>>16);
}
__device__ __forceinline__ float bf2f(unsigned short h){
  return __uint_as_float(((unsigned)h)<<16);
}

// ---------------------------------------------------------------- setup
__global__ void k_init(float* __restrict__ logdet){
  int t = threadIdx.x; if(t < NMAT) logdet[t] = 0.f;
}

__global__ void k_softmax_v(const float* __restrict__ Vc, float* __restrict__ V){
  int i = blockIdx.x*blockDim.x + threadIdx.x;
  if(i >= 1024) return;
  float4 v = ((const float4*)Vc)[i];
  float mx = fmaxf(fmaxf(v.x,v.y), fmaxf(v.z,v.w));
  float e0=__expf(v.x-mx), e1=__expf(v.y-mx), e2=__expf(v.z-mx), e3=__expf(v.w-mx);
  float is = 1.f/(e0+e1+e2+e3);
  ((float4*)V)[i] = make_float4(e0*is, e1*is, e2*is, e3*is);
}

// Pr[b,i] = V[i, x[b,i]];  PrInv = 1/Pr;  y[b] = sum_i log(Pr + 1e-7)
__global__ void k_pr_y(const float* __restrict__ V, const int* __restrict__ x,
                       float* __restrict__ PrInv, float* __restrict__ y){
  int b = blockIdx.x, t = threadIdx.x;
  __shared__ float red[256];
  float acc = 0.f;
  for(int i=t; i<1024; i+=256){
    int xv = x[b*1024+i];
    float pr = V[i*4+xv];
    PrInv[b*1024+i] = 1.f/pr;
    acc += logf(pr + 1e-7f);
  }
  red[t]=acc; __syncthreads();
  for(int s=128;s>0;s>>=1){ if(t<s) red[t]+=red[t+s]; __syncthreads(); }
  if(t==0) y[b]=red[0];
}

// Ws = sigmoid(W) strictly-lower, symmetrized, zero diag
__global__ void k_ws(const float* __restrict__ W, float* __restrict__ Ws){
  int idx = blockIdx.x*256 + threadIdx.x;
  int i = idx>>10, j = idx&1023;
  float v = 0.f;
  if(i != j){
    float w = (i>j) ? W[i*1024+j] : W[j*1024+i];
    v = 1.f/(1.f+__expf(-w));
  }
  Ws[idx]=v;
}

// ---------------------------------------------------------------- sinkhorn + WP
__global__ void __launch_bounds__(256) k_sinkhorn(
    const float* __restrict__ Ec, const float* __restrict__ V,
    const float* __restrict__ Ws, const float* __restrict__ PrInv,
    const int* __restrict__ x, float* __restrict__ mats, float* __restrict__ col0){
  int idx = blockIdx.x*256 + threadIdx.x;
  int i = idx>>10, j = idx&1023;
  if(i==0) return;                      // row 0 of WP never needed
  int t = threadIdx.x;
  __shared__ float sE[256][17];
  if(i==j){                             // diagonal blocks are zeroed by (1-eye)
    for(int b=0;b<32;b++)
      mats[(size_t)(1+b)*MSZ + (size_t)(i-1)*1024 + (j-1)] = 0.f;
    return;
  }
  float E[16];
  {
    const float4* p = (const float4*)(Ec + (size_t)idx*16);
    float4 q0=p[0], q1=p[1], q2=p[2], q3=p[3];
    E[0]=__expf(q0.x); E[1]=__expf(q0.y); E[2]=__expf(q0.z); E[3]=__expf(q0.w);
    E[4]=__expf(q1.x); E[5]=__expf(q1.y); E[6]=__expf(q1.z); E[7]=__expf(q1.w);
    E[8]=__expf(q2.x); E[9]=__expf(q2.y); E[10]=__expf(q2.z); E[11]=__expf(q2.w);
    E[12]=__expf(q3.x);E[13]=__expf(q3.y);E[14]=__expf(q3.z); E[15]=__expf(q3.w);
  }
  float s0=0.f;
  #pragma unroll
  for(int q=0;q<16;q++) s0+=E[q];
  float is0 = frcp(s0);
  #pragma unroll
  for(int q=0;q<16;q++) E[q]*=is0;
  float av[4], bv[4];
  {
    float4 va = ((const float4*)V)[i];
    av[0]=va.x; av[1]=va.y; av[2]=va.z; av[3]=va.w;
    float4 vb = ((const float4*)V)[j];
    bv[0]=vb.x; bv[1]=vb.y; bv[2]=vb.z; bv[3]=vb.w;
  }
  for(int it=0; it<40; ++it){
    #pragma unroll
    for(int r=0;r<4;r++){
      float rs = E[4*r]+E[4*r+1]+E[4*r+2]+E[4*r+3];
      float sc = av[r]*frcp(rs+1e-7f);
      E[4*r]*=sc; E[4*r+1]*=sc; E[4*r+2]*=sc; E[4*r+3]*=sc;
    }
    #pragma unroll
    for(int c=0;c<4;c++){
      float cs = E[c]+E[4+c]+E[8+c]+E[12+c];
      float sc = bv[c]*frcp(cs+1e-7f);
      E[c]*=sc; E[4+c]*=sc; E[8+c]*=sc; E[12+c]*=sc;
    }
    float T=0.f;
    #pragma unroll
    for(int q=0;q<16;q++) T+=E[q];
    float u = frcp(T+1e-7f);
    #pragma unroll
    for(int q=0;q<16;q++) E[q]*=u;
  }
  #pragma unroll
  for(int q=0;q<16;q++) sE[t][q] = fminf(fmaxf(E[q],0.f),1.f);
  float wsij = Ws[idx];
  for(int b=0;b<32;b++){
    int xi = x[b*1024+i];               // uniform per block -> scalar load
    int xj = x[b*1024+j];
    float val = sE[t][(xi<<2)+xj] * wsij * PrInv[b*1024+i] * PrInv[b*1024+j];
    if(j==0) col0[b*1024+i] = val;
    else mats[(size_t)(1+b)*MSZ + (size_t)(i-1)*1024 + (j-1)] = val;
  }
}

// ---------------------------------------------------------------- Laplacian builds
// Matrices padded to 1024x1024: row/col 1023 zero, A[1023][1023]=1 (log 1 = 0).

__global__ void k_l0(const float* __restrict__ Ws, float* __restrict__ mats){
  int r = blockIdx.x, t = threadIdx.x;
  float* orow = mats + (size_t)r*1024;
  if(r == 1023){
    float4 o = make_float4(0.f,0.f,0.f,0.f);
    if(t==255) o.w = 1.f;
    ((float4*)orow)[t] = o;
    return;
  }
  const float* wrow = Ws + (size_t)(r+1)*1024;
  float4 v = ((const float4*)wrow)[t];
  __shared__ float red[256];
  red[t] = v.x+v.y+v.z+v.w;             // full 1024-col row sum (Ws diag = 0)
  __syncthreads();
  for(int s=128;s>0;s>>=1){ if(t<s) red[t]+=red[t+s]; __syncthreads(); }
  float rs = red[0];
  float o[4];
  #pragma unroll
  for(int q=0;q<4;q++){
    int c = 4*t+q;
    if(c==r)          o[q] = rs + 1e-7f;
    else if(c < 1023) o[q] = 1e-7f - wrow[c+1];
    else              o[q] = 0.f;
  }
  ((float4*)orow)[t] = make_float4(o[0],o[1],o[2],o[3]);
}

__global__ void k_lb(float* __restrict__ mats, const float* __restrict__ col0){
  int r = blockIdx.x, b = blockIdx.y, t = threadIdx.x;
  float* row = mats + (size_t)(1+b)*MSZ + (size_t)r*1024;
  if(r == 1023){
    float4 o = make_float4(0.f,0.f,0.f,0.f);
    if(t==255) o.w = 1.f;
    ((float4*)row)[t] = o;
    return;
  }
  float4 v = ((const float4*)row)[t];
  bool last = (t==255);                 // col 1023 is padding (poison): exclude
  __shared__ float red[256];
  red[t] = v.x+v.y+v.z + (last?0.f:v.w);
  __syncthreads();
  for(int s=128;s>0;s>>=1){ if(t<s) red[t]+=red[t+s]; __syncthreads(); }
  float rs = red[0] + col0[b*1024 + r + 1];
  int c0 = 4*t;
  float o0 = (c0==r)  ? rs+1e-7f : 1e-7f - v.x;
  float o1 = (c0+1==r)? rs+1e-7f : 1e-7f - v.y;
  float o2 = (c0+2==r)? rs+1e-7f : 1e-7f - v.z;
  float o3 = last ? 0.f : ((c0+3==r)? rs+1e-7f : 1e-7f - v.w);
  ((float4*)row)[t] = make_float4(o0,o1,o2,o3);
}

// ---------------------------------------------------------------- blocked LU
__global__ void __launch_bounds__(64) k_diag(float* __restrict__ mats,
    float* __restrict__ L11g, float* __restrict__ U11g,
    float* __restrict__ logdet, int k){
  int m = blockIdx.x;
  const float* A = mats + (size_t)m*MSZ;
  int t = threadIdx.x;
  float row[64];
  #pragma unroll
  for(int q=0;q<64;q++)
    row[q] = A[(size_t)(k+t)*1024 + k + q];
  float slog = 0.f;
  #pragma unroll
  for(int c=0;c<64;c++){
    float piv = __shfl(row[c], c);
    slog += logf(fabsf(piv));
    float ip = frcp(piv);
    bool below = t > c;
    float lic = below ? row[c]*ip : 0.f;
    row[c] = below ? lic : row[c];
    if(below) L11g[m*4096 + t*64 + c] = lic;
    #pragma unroll
    for(int q=c+1;q<64;q++){
      float uq = __shfl(row[q], c);
      row[q] = fmaf(-lic, uq, row[q]);
    }
  }
  #pragma unroll
  for(int q=0;q<64;q++)
    U11g[m*4096 + t*64 + q] = (q>=t) ? row[q] : 0.f;
  if(t==0) logdet[m] += slog;
}

// Fused panel solves (independent of each other)
__global__ void __launch_bounds__(256) k_panel(float* __restrict__ mats,
    const float* __restrict__ L11g, const float* __restrict__ U11g, int k){
  int m = blockIdx.y;
  float* A = mats + (size_t)m*MSZ;
  int rem = 1024 - (k+64);
  int nb = (rem + 255) >> 8;
  int t = threadIdx.x;
  if((int)blockIdx.x < nb){
    // ---- L21 = A21 * U11^-1
    const float* __restrict__ U = U11g + m*4096;
    int i = k + 64 + blockIdx.x*256 + t;
    bool act = i < 1024;
    size_t base = (size_t)i*1024 + k;
    float xr[64];
    const float4* pb = (const float4*)(A + (act ? base : 0));
    #pragma unroll
    for(int q4=0;q4<16;q4++){
      float4 v = act ? pb[q4] : make_float4(0.f,0.f,0.f,0.f);
      xr[4*q4]=v.x; xr[4*q4+1]=v.y; xr[4*q4+2]=v.z; xr[4*q4+3]=v.w;
    }
    #pragma unroll
    for(int p=0;p<64;p++){
      float xp = xr[p]*frcp(U[p*64+p]);
      xr[p] = xp;
      #pragma unroll
      for(int q=p+1;q<64;q++) xr[q] = fmaf(-xp, U[p*64+q], xr[q]);
    }
    if(act){
      float4* po = (float4*)(A + base);
      #pragma unroll
      for(int q4=0;q4<16;q4++)
        po[q4] = make_float4(xr[4*q4],xr[4*q4+1],xr[4*q4+2],xr[4*q4+3]);
    }
  } else {
    // ---- U12 = L11^-1 * A12
    const float* __restrict__ L = L11g + m*4096;
    int col = k + 64 + (blockIdx.x - nb)*256 + t;
    bool act = col < 1024;
    float tv[64];
    #pragma unroll
    for(int r=0;r<64;r++) tv[r] = act ? A[(size_t)(k+r)*1024 + col] : 0.f;
    #pragma unroll
    for(int r=1;r<64;r++){
      float s = tv[r];
      #pragma unroll
      for(int p=0;p<r;p++) s = fmaf(-L[r*64+p], tv[p], s);
      tv[r] = s;
    }
    if(act){
      #pragma unroll
      for(int r=0;r<64;r++) A[(size_t)(k+r)*1024 + col] = tv[r];
    }
  }
}

// ------------------------------------------------------- MFMA split-bf16 Schur
// A22 -= L21 * U12.  128x128 C tile, 4 waves (each 64x64), K=64 staged in two
// 32-chunks.  fp32 operands split hi+lo bf16; D = Ah*Bh + Ah*Bl + Al*Bh via
// v_mfma_f32_32x32x16_bf16.  LDS planes octet-XOR-swizzled => conflict-free
// b128 frag reads.
__global__ void __launch_bounds__(256) k_gemm(float* __restrict__ mats, int k){
  int m = blockIdx.z;
  float* A = mats + (size_t)m*MSZ;
  int r0 = k + 64;
  int i0 = r0 + blockIdx.y*128;
  int j0 = r0 + blockIdx.x*128;
  __shared__ unsigned short As[2][4096];   // [hi/lo][row*32 + swz(k)]
  __shared__ unsigned short Bs[2][4096];   // [hi/lo][col*32 + swz(k)]
  int t = threadIdx.x;
  int lane = t & 63, wv = t >> 6;
  int wr = wv >> 1, wc = wv & 1;

  f32x16 acc[2][2];
  #pragma unroll
  for(int rt=0;rt<2;rt++)
    #pragma unroll
    for(int ct=0;ct<2;ct++)
      #pragma unroll
      for(int q=0;q<16;q++) acc[rt][ct][q] = 0.f;

  for(int ks=0; ks<64; ks+=32){
    if(ks) __syncthreads();
    // ---- stage A21 block: rows i0..i0+127, cols k+ks..+31
    {
      int c4 = t & 7;                 // k-quad
      int rb = t >> 3;                // 0..31
      #pragma unroll
      for(int p=0;p<4;p++){
        int row = rb + 32*p;
        int gi = i0 + row;
        float4 v = (gi < 1024) ? *(const float4*)(A + (size_t)gi*1024 + k + ks + c4*4)
                               : make_float4(0.f,0.f,0.f,0.f);
        ushort4 h = make_ushort4(bf16rn(v.x),bf16rn(v.y),bf16rn(v.z),bf16rn(v.w));
        ushort4 l = make_ushort4(bf16rn(v.x-bf2f(h.x)), bf16rn(v.y-bf2f(h.y)),
                                 bf16rn(v.z-bf2f(h.z)), bf16rn(v.w-bf2f(h.w)));
        int base = row*32 + (((c4>>1) ^ (row&3))<<3) + (c4&1)*4;
        *(ushort4*)&As[0][base] = h;
        *(ushort4*)&As[1][base] = l;
      }
    }
    // ---- stage U12 block transposed: rows k+ks..+31, cols j0..j0+127
    {
      int cq = t & 31;                // col-quad
      int kq = t >> 5;                // k-quad 0..7
      int gj = j0 + cq*4;
      bool cv = gj < 1024;
      float4 r0v = cv ? *(const float4*)(A + (size_t)(k+ks+kq*4+0)*1024 + gj) : make_float4(0,0,0,0);
      float4 r1v = cv ? *(const float4*)(A + (size_t)(k+ks+kq*4+1)*1024 + gj) : make_float4(0,0,0,0);
      float4 r2v = cv ? *(const float4*)(A + (size_t)(k+ks+kq*4+2)*1024 + gj) : make_float4(0,0,0,0);
      float4 r3v = cv ? *(const float4*)(A + (size_t)(k+ks+kq*4+3)*1024 + gj) : make_float4(0,0,0,0);
      const float* rr[4] = {&r0v.x, &r1v.x, &r2v.x, &r3v.x};
      #pragma unroll
      for(int c=0;c<4;c++){
        float v0 = rr[0][c], v1 = rr[1][c], v2 = rr[2][c], v3 = rr[3][c];
        ushort4 h = make_ushort4(bf16rn(v0),bf16rn(v1),bf16rn(v2),bf16rn(v3));
        ushort4 l = make_ushort4(bf16rn(v0-bf2f(h.x)), bf16rn(v1-bf2f(h.y)),
                                 bf16rn(v2-bf2f(h.z)), bf16rn(v3-bf2f(h.w)));
        int col = cq*4 + c;
        int base = col*32 + (((kq>>1) ^ (col&3))<<3) + (kq&1)*4;
        *(ushort4*)&Bs[0][base] = h;
        *(ushort4*)&Bs[1][base] = l;
      }
    }
    __syncthreads();
    // ---- MFMA over this K=32 stage (2 chunks of 16)
    int kgrp = lane >> 5;
    #pragma unroll
    for(int kc=0;kc<2;kc++){
      int koct = kc*2 + kgrp;
      bfrag ah[2], al[2], bh[2], bl[2];
      #pragma unroll
      for(int rt=0;rt<2;rt++){
        int row = wr*64 + rt*32 + (lane&31);
        int ad = row*32 + ((koct ^ (row&3))<<3);
        ah[rt] = *(const bfrag*)&As[0][ad];
        al[rt] = *(const bfrag*)&As[1][ad];
      }
      #pragma unroll
      for(int ct=0;ct<2;ct++){
        int col = wc*64 + ct*32 + (lane&31);
        int ad = col*32 + ((koct ^ (col&3))<<3);
        bh[ct] = *(const bfrag*)&Bs[0][ad];
        bl[ct] = *(const bfrag*)&Bs[1][ad];
      }
      #pragma unroll
      for(int rt=0;rt<2;rt++)
        #pragma unroll
        for(int ct=0;ct<2;ct++){
          acc[rt][ct] = __builtin_amdgcn_mfma_f32_32x32x16_bf16(ah[rt], bh[ct], acc[rt][ct], 0,0,0);
          acc[rt][ct] = __builtin_amdgcn_mfma_f32_32x32x16_bf16(ah[rt], bl[ct], acc[rt][ct], 0,0,0);
          acc[rt][ct] = __builtin_amdgcn_mfma_f32_32x32x16_bf16(al[rt], bh[ct], acc[rt][ct], 0,0,0);
        }
    }
  }
  // ---- C RMW epilogue (C/D layout: col=lane&31, row=(reg&3)+8*(reg>>2)+4*(lane>>5))
  #pragma unroll
  for(int rt=0;rt<2;rt++){
    #pragma unroll
    for(int ct=0;ct<2;ct++){
      int col = j0 + wc*64 + ct*32 + (lane&31);
      int rbase = i0 + wr*64 + rt*32 + ((lane>>5)<<2);
      if(col < 1024){
        #pragma unroll
        for(int reg=0;reg<16;reg++){
          int row = rbase + (reg&3) + ((reg>>2)<<3);
          if(row < 1024){
            float* pc = A + (size_t)row*1024 + col;
            *pc -= acc[rt][ct][reg];
          }
        }
      }
    }
  }
}

__global__ void k_final(const float* __restrict__ y, const float* __restrict__ logdet,
                        float* __restrict__ out){
  int b = threadIdx.x;
  if(b<32) out[b] = y[b] + logdet[1+b] - logdet[0];
}

// ---------------------------------------------------------------- launch
extern "C" void kernel_launch(void* const* d_in, const int* in_sizes, int n_in,
                              void* d_out, int out_size, void* d_ws, size_t ws_size,
                              hipStream_t stream){
  (void)in_sizes; (void)n_in; (void)out_size; (void)ws_size;
  const int*   x  = (const int*)d_in[0];
  const float* W  = (const float*)d_in[1];
  const float* Vc = (const float*)d_in[2];
  const float* Ec = (const float*)d_in[3];
  float* out = (float*)d_out;

  char* p = (char*)d_ws;
  auto alloc = [&](size_t bytes)->char*{ char* r = p; p += (bytes+255)&~(size_t)255; return r; };
  float* mats   = (float*)alloc((size_t)NMAT*MSZ*4);   // 138.4 MB
  float* Ws     = (float*)alloc(1048576ull*4);
  float* L11g   = (float*)alloc((size_t)NMAT*4096*4);
  float* U11g   = (float*)alloc((size_t)NMAT*4096*4);
  float* V      = (float*)alloc(4096*4);
  float* PrInv  = (float*)alloc(32768*4);
  float* col0   = (float*)alloc(32768*4);
  float* y      = (float*)alloc(256);
  float* logdet = (float*)alloc(256);

  k_init<<<1,64,0,stream>>>(logdet);
  k_softmax_v<<<4,256,0,stream>>>(Vc, V);
  k_pr_y<<<32,256,0,stream>>>(V, x, PrInv, y);
  k_ws<<<4096,256,0,stream>>>(W, Ws);
  k_sinkhorn<<<4096,256,0,stream>>>(Ec, V, Ws, PrInv, x, mats, col0);
  k_l0<<<1024,256,0,stream>>>(Ws, mats);
  k_lb<<<dim3(1024,32),256,0,stream>>>(mats, col0);

  for(int s=0;s<16;s++){
    int k = 64*s;
    k_diag<<<NMAT,64,0,stream>>>(mats, L11g, U11g, logdet, k);
    int rem = 1024 - (k+64);
    if(rem > 0){
      int nbp = (rem+255)/256;
      k_panel<<<dim3(2*nbp,NMAT),256,0,stream>>>(mats, L11g, U11g, k);
      int nt = (rem+127)/128;
      k_gemm<<<dim3(nt,nt,NMAT),256,0,stream>>>(mats, k);
    }
  }
  k_final<<<1,32,0,stream>>>(y, logdet, out);
}

// Round 4
// 1457.107 us; speedup vs baseline: 1.5358x; 1.5358x over previous
//
#include <hip/hip_runtime.h>
#include <math.h>

#define MSZ   1048576ull  // 1024*1024 elements per matrix slot
#define NMAT  33          // matrix 0 = L0, matrices 1..32 = per-batch L
#define PANSZ 61440       // 960*64 shorts per matrix per panel plane

__device__ __forceinline__ float frcp(float x){ return __builtin_amdgcn_rcpf(x); }

typedef __attribute__((ext_vector_type(8)))  short  bfrag;   // 8 x bf16 (4 VGPR)
typedef __attribute__((ext_vector_type(8)))  unsigned short u16x8;
typedef __attribute__((ext_vector_type(16))) float  f32x16;  // 32x32 acc

__device__ __forceinline__ unsigned short bf16rn(float x){
  unsigned u = __float_as_uint(x);
  unsigned r = u + 0x7fffu + ((u>>16)&1u);
  return (unsigned short)(r>>16);
}
__device__ __forceinline__ float bf2f(unsigned short h){
  return __uint_as_float(((unsigned)h)<<16);
}

// ---------------------------------------------------------------- setup
__global__ void k_softmax_v(const float* __restrict__ Vc, float* __restrict__ V){
  int i = blockIdx.x*blockDim.x + threadIdx.x;
  if(i >= 1024) return;
  float4 v = ((const float4*)Vc)[i];
  float mx = fmaxf(fmaxf(v.x,v.y), fmaxf(v.z,v.w));
  float e0=__expf(v.x-mx), e1=__expf(v.y-mx), e2=__expf(v.z-mx), e3=__expf(v.w-mx);
  float is = 1.f/(e0+e1+e2+e3);
  ((float4*)V)[i] = make_float4(e0*is, e1*is, e2*is, e3*is);
}

__global__ void k_pr_y(const float* __restrict__ V, const int* __restrict__ x,
                       float* __restrict__ PrInv, float* __restrict__ y){
  int b = blockIdx.x, t = threadIdx.x;
  __shared__ float red[256];
  float acc = 0.f;
  for(int i=t; i<1024; i+=256){
    int xv = x[b*1024+i];
    float pr = V[i*4+xv];
    PrInv[b*1024+i] = 1.f/pr;
    acc += logf(pr + 1e-7f);
  }
  red[t]=acc; __syncthreads();
  for(int s=128;s>0;s>>=1){ if(t<s) red[t]+=red[t+s]; __syncthreads(); }
  if(t==0) y[b]=red[0];
}

__global__ void k_ws(const float* __restrict__ W, float* __restrict__ Ws){
  int idx = blockIdx.x*256 + threadIdx.x;
  int i = idx>>10, j = idx&1023;
  float v = 0.f;
  if(i != j){
    float w = (i>j) ? W[i*1024+j] : W[j*1024+i];
    v = 1.f/(1.f+__expf(-w));
  }
  Ws[idx]=v;
}

// ---------------------------------------------------------------- sinkhorn + WP
// Total-renormalization dropped: after the column step, sum(E) = sum(bv) = 1
// up to O(1e-7), so the reference's third normalization is a near-no-op.
__global__ void __launch_bounds__(256) k_sinkhorn(
    const float* __restrict__ Ec, const float* __restrict__ V,
    const float* __restrict__ Ws, const float* __restrict__ PrInv,
    const int* __restrict__ x, float* __restrict__ mats, float* __restrict__ col0){
  int idx = blockIdx.x*256 + threadIdx.x;
  int i = idx>>10, j = idx&1023;
  if(i==0) return;                      // row 0 of WP never needed
  int t = threadIdx.x;
  __shared__ float sE[256][17];
  if(i==j){                             // diagonal blocks are zeroed by (1-eye)
    for(int b=0;b<32;b++)
      mats[(size_t)(1+b)*MSZ + (size_t)(i-1)*1024 + (j-1)] = 0.f;
    return;
  }
  float E[16];
  {
    const float4* p = (const float4*)(Ec + (size_t)idx*16);
    float4 q0=p[0], q1=p[1], q2=p[2], q3=p[3];
    E[0]=__expf(q0.x); E[1]=__expf(q0.y); E[2]=__expf(q0.z); E[3]=__expf(q0.w);
    E[4]=__expf(q1.x); E[5]=__expf(q1.y); E[6]=__expf(q1.z); E[7]=__expf(q1.w);
    E[8]=__expf(q2.x); E[9]=__expf(q2.y); E[10]=__expf(q2.z); E[11]=__expf(q2.w);
    E[12]=__expf(q3.x);E[13]=__expf(q3.y);E[14]=__expf(q3.z); E[15]=__expf(q3.w);
  }
  float s0=0.f;
  #pragma unroll
  for(int q=0;q<16;q++) s0+=E[q];
  float is0 = frcp(s0);
  #pragma unroll
  for(int q=0;q<16;q++) E[q]*=is0;
  float av[4], bv[4];
  {
    float4 va = ((const float4*)V)[i];
    av[0]=va.x; av[1]=va.y; av[2]=va.z; av[3]=va.w;
    float4 vb = ((const float4*)V)[j];
    bv[0]=vb.x; bv[1]=vb.y; bv[2]=vb.z; bv[3]=vb.w;
  }
  for(int it=0; it<40; ++it){
    #pragma unroll
    for(int r=0;r<4;r++){
      float rs = E[4*r]+E[4*r+1]+E[4*r+2]+E[4*r+3];
      float sc = av[r]*frcp(rs+1e-7f);
      E[4*r]*=sc; E[4*r+1]*=sc; E[4*r+2]*=sc; E[4*r+3]*=sc;
    }
    #pragma unroll
    for(int c=0;c<4;c++){
      float cs = E[c]+E[4+c]+E[8+c]+E[12+c];
      float sc = bv[c]*frcp(cs+1e-7f);
      E[c]*=sc; E[4+c]*=sc; E[8+c]*=sc; E[12+c]*=sc;
    }
  }
  #pragma unroll
  for(int q=0;q<16;q++) sE[t][q] = fminf(fmaxf(E[q],0.f),1.f);
  float wsij = Ws[idx];
  for(int b=0;b<32;b++){
    int xi = x[b*1024+i];               // uniform per block -> scalar load
    int xj = x[b*1024+j];
    float val = sE[t][(xi<<2)+xj] * wsij * PrInv[b*1024+i] * PrInv[b*1024+j];
    if(j==0) col0[b*1024+i] = val;
    else mats[(size_t)(1+b)*MSZ + (size_t)(i-1)*1024 + (j-1)] = val;
  }
}

// ---------------------------------------------------------------- Laplacian build
// Matrices padded to 1024x1024: row/col 1023 zero, A[1023][1023]=1 (log 1 = 0).
// z==0: L0 from Ws.  z>=1: in-place WP -> L for batch z-1.
__global__ void k_lap(const float* __restrict__ Ws, float* __restrict__ mats,
                      const float* __restrict__ col0){
  int r = blockIdx.x, z = blockIdx.y, t = threadIdx.x;
  __shared__ float red[256];
  if(z == 0){
    float* orow = mats + (size_t)r*1024;
    if(r == 1023){
      float4 o = make_float4(0.f,0.f,0.f,0.f);
      if(t==255) o.w = 1.f;
      ((float4*)orow)[t] = o;
      return;
    }
    const float* wrow = Ws + (size_t)(r+1)*1024;
    float4 v = ((const float4*)wrow)[t];
    red[t] = v.x+v.y+v.z+v.w;           // full 1024-col row sum (Ws diag = 0)
    __syncthreads();
    for(int s=128;s>0;s>>=1){ if(t<s) red[t]+=red[t+s]; __syncthreads(); }
    float rs = red[0];
    float o[4];
    #pragma unroll
    for(int q=0;q<4;q++){
      int c = 4*t+q;
      if(c==r)          o[q] = rs + 1e-7f;
      else if(c < 1023) o[q] = 1e-7f - wrow[c+1];
      else              o[q] = 0.f;
    }
    ((float4*)orow)[t] = make_float4(o[0],o[1],o[2],o[3]);
  } else {
    int b = z-1;
    float* row = mats + (size_t)(1+b)*MSZ + (size_t)r*1024;
    if(r == 1023){
      float4 o = make_float4(0.f,0.f,0.f,0.f);
      if(t==255) o.w = 1.f;
      ((float4*)row)[t] = o;
      return;
    }
    float4 v = ((const float4*)row)[t];
    bool last = (t==255);               // col 1023 is padding (poison): exclude
    red[t] = v.x+v.y+v.z + (last?0.f:v.w);
    __syncthreads();
    for(int s=128;s>0;s>>=1){ if(t<s) red[t]+=red[t+s]; __syncthreads(); }
    float rs = red[0] + col0[b*1024 + r + 1];
    int c0 = 4*t;
    float o0 = (c0==r)  ? rs+1e-7f : 1e-7f - v.x;
    float o1 = (c0+1==r)? rs+1e-7f : 1e-7f - v.y;
    float o2 = (c0+2==r)? rs+1e-7f : 1e-7f - v.z;
    float o3 = last ? 0.f : ((c0+3==r)? rs+1e-7f : 1e-7f - v.w);
    ((float4*)row)[t] = make_float4(o0,o1,o2,o3);
  }
}

// ---------------------------------------------------------------- blocked LU
__global__ void __launch_bounds__(64) k_diag(float* __restrict__ mats,
    float* __restrict__ L11g, float* __restrict__ U11g,
    float* __restrict__ logdet, int k){
  int m = blockIdx.x;
  const float* A = mats + (size_t)m*MSZ;
  int t = threadIdx.x;
  float row[64];
  #pragma unroll
  for(int q=0;q<64;q++)
    row[q] = A[(size_t)(k+t)*1024 + k + q];
  float slog = 0.f;
  #pragma unroll
  for(int c=0;c<64;c++){
    float piv = __shfl(row[c], c);
    slog += logf(fabsf(piv));
    float ip = frcp(piv);
    bool below = t > c;
    float lic = below ? row[c]*ip : 0.f;
    row[c] = below ? lic : row[c];
    if(below) L11g[m*4096 + t*64 + c] = lic;
    #pragma unroll
    for(int q=c+1;q<64;q++){
      float uq = __shfl(row[q], c);
      row[q] = fmaf(-lic, uq, row[q]);
    }
  }
  #pragma unroll
  for(int q=0;q<64;q++)
    U11g[m*4096 + t*64 + q] = (q>=t) ? row[q] : 0.f;
  if(t==0){ if(k==0) logdet[m] = slog; else logdet[m] += slog; }
}

// Panel solves; outputs written ONLY as pre-split bf16 hi/lo panels in the
// gemm's [row][k] layout (fp32 write-back dropped — L21/U12 are final factors,
// read again only by k_gemm).
__global__ void __launch_bounds__(256) k_panel(float* __restrict__ mats,
    const float* __restrict__ L11g, const float* __restrict__ U11g,
    unsigned short* __restrict__ Ah, unsigned short* __restrict__ Al,
    unsigned short* __restrict__ Bh, unsigned short* __restrict__ Bl, int k){
  int m = blockIdx.y;
  float* A = mats + (size_t)m*MSZ;
  int rem = 1024 - (k+64);
  int nb = (rem + 255) >> 8;
  int t = threadIdx.x;
  float v[64];
  unsigned short* Ph; unsigned short* Pl; int rel; bool act;
  if((int)blockIdx.x < nb){
    // ---- L21 = A21 * U11^-1  (thread per trailing row)
    const float* __restrict__ U = U11g + m*4096;
    rel = blockIdx.x*256 + t;
    act = rel < rem;
    int i = k + 64 + rel;
    size_t base = (size_t)i*1024 + k;
    const float4* pb = (const float4*)(A + (act ? base : 0));
    #pragma unroll
    for(int q4=0;q4<16;q4++){
      float4 w = act ? pb[q4] : make_float4(0.f,0.f,0.f,0.f);
      v[4*q4]=w.x; v[4*q4+1]=w.y; v[4*q4+2]=w.z; v[4*q4+3]=w.w;
    }
    #pragma unroll
    for(int p=0;p<64;p++){
      float xp = v[p]*frcp(U[p*64+p]);
      v[p] = xp;
      #pragma unroll
      for(int q=p+1;q<64;q++) v[q] = fmaf(-xp, U[p*64+q], v[q]);
    }
    Ph = Ah + (size_t)m*PANSZ; Pl = Al + (size_t)m*PANSZ;
  } else {
    // ---- U12 = L11^-1 * A12  (thread per trailing column)
    const float* __restrict__ L = L11g + m*4096;
    rel = (blockIdx.x - nb)*256 + t;
    act = rel < rem;
    int col = k + 64 + rel;
    #pragma unroll
    for(int r=0;r<64;r++) v[r] = act ? A[(size_t)(k+r)*1024 + col] : 0.f;
    #pragma unroll
    for(int r=1;r<64;r++){
      float s = v[r];
      #pragma unroll
      for(int p=0;p<r;p++) s = fmaf(-L[r*64+p], v[p], s);
      v[r] = s;
    }
    Ph = Bh + (size_t)m*PANSZ; Pl = Bl + (size_t)m*PANSZ;
  }
  if(act){
    u16x8* ph = (u16x8*)(Ph + (size_t)rel*64);
    u16x8* pl = (u16x8*)(Pl + (size_t)rel*64);
    #pragma unroll
    for(int q8=0;q8<8;q8++){
      u16x8 h8, l8;
      #pragma unroll
      for(int e=0;e<8;e++){
        float x = v[q8*8+e];
        unsigned short h = bf16rn(x);
        h8[e] = h;
        l8[e] = bf16rn(x - bf2f(h));
      }
      ph[q8] = h8;
      pl[q8] = l8;
    }
  }
}

// ------------------------------------------------------- MFMA split-bf16 Schur
// A22 -= L21 * U12.  128x128 C tile, 4 waves (each 64x64 of 32x32 MFMAs), K=64
// single stage.  Panels arrive pre-split bf16 hi/lo: staging is pure 16B copies
// (no conversion).  D = Ah*Bh + Ah*Bl + Al*Bh via v_mfma_f32_32x32x16_bf16.
__global__ void __launch_bounds__(256) k_gemm(float* __restrict__ mats,
    const unsigned short* __restrict__ Ah, const unsigned short* __restrict__ Al,
    const unsigned short* __restrict__ Bh, const unsigned short* __restrict__ Bl,
    int k){
  int m = blockIdx.z;
  float* A = mats + (size_t)m*MSZ;
  int rem = 1024 - (k+64);
  int i0rel = blockIdx.y*128;
  int j0rel = blockIdx.x*128;
  __shared__ unsigned short As[2][8192];   // [hi/lo][row*64 + swz(koct)*8]
  __shared__ unsigned short Bs[2][8192];   // [hi/lo][col*64 + swz(koct)*8]
  int t = threadIdx.x;
  int lane = t & 63, wv = t >> 6;
  int wr = wv >> 1, wc = wv & 1;

  const unsigned short* pAh = Ah + (size_t)m*PANSZ;
  const unsigned short* pAl = Al + (size_t)m*PANSZ;
  const unsigned short* pBh = Bh + (size_t)m*PANSZ;
  const unsigned short* pBl = Bl + (size_t)m*PANSZ;

  // stage: 128 rows x 8 octets = 1024 16B-chunks per plane, 4 per thread
  #pragma unroll
  for(int p=0;p<4;p++){
    int c = t + 256*p;
    int row = c>>3, koct = c&7;
    int lo = row*64 + ((koct ^ (row&7))<<3);
    u16x8 z; z = 0;
    {
      int gr = i0rel + row;
      u16x8 vh = (gr<rem) ? *(const u16x8*)(pAh + (size_t)gr*64 + koct*8) : z;
      u16x8 vl = (gr<rem) ? *(const u16x8*)(pAl + (size_t)gr*64 + koct*8) : z;
      *(u16x8*)&As[0][lo] = vh;
      *(u16x8*)&As[1][lo] = vl;
    }
    {
      int gc = j0rel + row;
      u16x8 vh = (gc<rem) ? *(const u16x8*)(pBh + (size_t)gc*64 + koct*8) : z;
      u16x8 vl = (gc<rem) ? *(const u16x8*)(pBl + (size_t)gc*64 + koct*8) : z;
      *(u16x8*)&Bs[0][lo] = vh;
      *(u16x8*)&Bs[1][lo] = vl;
    }
  }
  __syncthreads();

  f32x16 acc[2][2];
  #pragma unroll
  for(int rt=0;rt<2;rt++)
    #pragma unroll
    for(int ct=0;ct<2;ct++)
      #pragma unroll
      for(int q=0;q<16;q++) acc[rt][ct][q] = 0.f;

  int kgrp = lane >> 5;
  #pragma unroll
  for(int kc=0;kc<4;kc++){
    int koct = kc*2 + kgrp;
    bfrag ah[2], al[2], bh[2], bl[2];
    #pragma unroll
    for(int rt=0;rt<2;rt++){
      int row = wr*64 + rt*32 + (lane&31);
      int ad = row*64 + ((koct ^ (row&7))<<3);
      ah[rt] = *(const bfrag*)&As[0][ad];
      al[rt] = *(const bfrag*)&As[1][ad];
    }
    #pragma unroll
    for(int ct=0;ct<2;ct++){
      int col = wc*64 + ct*32 + (lane&31);
      int ad = col*64 + ((koct ^ (col&7))<<3);
      bh[ct] = *(const bfrag*)&Bs[0][ad];
      bl[ct] = *(const bfrag*)&Bs[1][ad];
    }
    #pragma unroll
    for(int rt=0;rt<2;rt++)
      #pragma unroll
      for(int ct=0;ct<2;ct++){
        acc[rt][ct] = __builtin_amdgcn_mfma_f32_32x32x16_bf16(ah[rt], bh[ct], acc[rt][ct], 0,0,0);
        acc[rt][ct] = __builtin_amdgcn_mfma_f32_32x32x16_bf16(ah[rt], bl[ct], acc[rt][ct], 0,0,0);
        acc[rt][ct] = __builtin_amdgcn_mfma_f32_32x32x16_bf16(al[rt], bh[ct], acc[rt][ct], 0,0,0);
      }
  }

  // C RMW epilogue (C/D layout: col=lane&31, row=(reg&3)+8*(reg>>2)+4*(lane>>5))
  int r0 = k + 64;
  #pragma unroll
  for(int rt=0;rt<2;rt++){
    int rowblk = i0rel + wr*64 + rt*32;
    if(rowblk >= rem) continue;
    #pragma unroll
    for(int ct=0;ct<2;ct++){
      int colblk = j0rel + wc*64 + ct*32;
      if(colblk >= rem) continue;
      int col = r0 + colblk + (lane&31);
      int rbase = r0 + rowblk + ((lane>>5)<<2);
      #pragma unroll
      for(int reg=0;reg<16;reg++){
        int row = rbase + (reg&3) + ((reg>>2)<<3);
        float* pc = A + (size_t)row*1024 + col;
        *pc -= acc[rt][ct][reg];
      }
    }
  }
}

__global__ void k_final(const float* __restrict__ y, const float* __restrict__ logdet,
                        float* __restrict__ out){
  int b = threadIdx.x;
  if(b<32) out[b] = y[b] + logdet[1+b] - logdet[0];
}

// ---------------------------------------------------------------- launch
extern "C" void kernel_launch(void* const* d_in, const int* in_sizes, int n_in,
                              void* d_out, int out_size, void* d_ws, size_t ws_size,
                              hipStream_t stream){
  (void)in_sizes; (void)n_in; (void)out_size; (void)ws_size;
  const int*   x  = (const int*)d_in[0];
  const float* W  = (const float*)d_in[1];
  const float* Vc = (const float*)d_in[2];
  const float* Ec = (const float*)d_in[3];
  float* out = (float*)d_out;

  char* p = (char*)d_ws;
  auto alloc = [&](size_t bytes)->char*{ char* r = p; p += (bytes+255)&~(size_t)255; return r; };
  float* mats   = (float*)alloc((size_t)NMAT*MSZ*4);           // 138.4 MB
  float* Ws     = (float*)alloc(1048576ull*4);
  float* L11g   = (float*)alloc((size_t)NMAT*4096*4);
  float* U11g   = (float*)alloc((size_t)NMAT*4096*4);
  unsigned short* Ah = (unsigned short*)alloc((size_t)NMAT*PANSZ*2);  // 4.05 MB each
  unsigned short* Al = (unsigned short*)alloc((size_t)NMAT*PANSZ*2);
  unsigned short* Bh = (unsigned short*)alloc((size_t)NMAT*PANSZ*2);
  unsigned short* Bl = (unsigned short*)alloc((size_t)NMAT*PANSZ*2);
  float* V      = (float*)alloc(4096*4);
  float* PrInv  = (float*)alloc(32768*4);
  float* col0   = (float*)alloc(32768*4);
  float* y      = (float*)alloc(256);
  float* logdet = (float*)alloc(256);

  k_softmax_v<<<4,256,0,stream>>>(Vc, V);
  k_pr_y<<<32,256,0,stream>>>(V, x, PrInv, y);
  k_ws<<<4096,256,0,stream>>>(W, Ws);
  k_sinkhorn<<<4096,256,0,stream>>>(Ec, V, Ws, PrInv, x, mats, col0);
  k_lap<<<dim3(1024,NMAT),256,0,stream>>>(Ws, mats, col0);

  for(int s=0;s<16;s++){
    int k = 64*s;
    k_diag<<<NMAT,64,0,stream>>>(mats, L11g, U11g, logdet, k);
    int rem = 1024 - (k+64);
    if(rem > 0){
      int nbp = (rem+255)/256;
      k_panel<<<dim3(2*nbp,NMAT),256,0,stream>>>(mats, L11g, U11g, Ah, Al, Bh, Bl, k);
      int nt = (rem+127)/128;
      k_gemm<<<dim3(nt,nt,NMAT),256,0,stream>>>(mats, Ah, Al, Bh, Bl, k);
    }
  }
  k_final<<<1,32,0,stream>>>(y, logdet, out);
}